// Round 20
// baseline (278.012 us; speedup 1.0000x reference)
//
#include <hip/hip_runtime.h>

#define NODES 50000
#define NBIN 196          // ceil(50000/256) dst-bins of 256 nodes
#define EPB 4096          // edges per partition block

typedef __attribute__((ext_vector_type(8))) short short8;
typedef __attribute__((ext_vector_type(4))) float f32x4;
typedef __attribute__((ext_vector_type(2))) float f32x2;

__device__ __forceinline__ ushort f2bf(float f) {
    uint u = __float_as_uint(f);
    uint r = (u + 0x7fffu + ((u >> 16) & 1u)) >> 16;
    return (ushort)r;
}
__device__ __forceinline__ float bf2f(ushort u) {
    return __uint_as_float(((uint)u) << 16);
}
__device__ __forceinline__ uchar f2fp8(float f) {
    return (uchar)(__builtin_amdgcn_cvt_pk_fp8_f32(f, f, 0, false) & 0xff);
}
// HW packed f32x2 -> bf16x2 (RNE), one VALU op
__device__ __forceinline__ uint cvtpk_bf16(float lo, float hi) {
    uint r;
    asm("v_cvt_pk_bf16_f32 %0, %1, %2" : "=v"(r) : "v"(lo), "v"(hi));
    return r;
}

// ---------------- atomic-free two-level CSR build ----------------

__global__ __launch_bounds__(256) void k_hist(const int* __restrict__ dst, int E,
                                              int* __restrict__ hist, int nblk) {
    __shared__ int h[NBIN];
    int t = threadIdx.x;
    for (int i = t; i < NBIN; i += 256) h[i] = 0;
    __syncthreads();
    int base = blockIdx.x * EPB;
#pragma unroll
    for (int i = 0; i < EPB / 256; ++i) {
        int e = base + i * 256 + t;
        if (e < E) atomicAdd(&h[dst[e] >> 8], 1);
    }
    __syncthreads();
    for (int i = t; i < NBIN; i += 256) hist[i * nblk + blockIdx.x] = h[i];
}

__global__ __launch_bounds__(1024) void k_scanbin(const int* __restrict__ hist,
                                                  int* __restrict__ offl,
                                                  int* __restrict__ btot, int nblk) {
    __shared__ int s[1024];
    int b = blockIdx.x, t = threadIdx.x;
    int v = (t < nblk) ? hist[b * nblk + t] : 0;
    s[t] = v;
    __syncthreads();
    for (int off = 1; off < 1024; off <<= 1) {
        int u = (t >= off) ? s[t - off] : 0;
        __syncthreads();
        s[t] += u;
        __syncthreads();
    }
    if (t < nblk) offl[b * nblk + t] = s[t] - v;
    if (t == 1023) btot[b] = s[1023];
}

__global__ __launch_bounds__(256) void k_scanoff(const int* __restrict__ btot,
                                                 int* __restrict__ binoff,
                                                 int* __restrict__ rowstart, int E) {
    __shared__ int s[256];
    int t = threadIdx.x;
    int v = (t < NBIN) ? btot[t] : 0;
    s[t] = v;
    __syncthreads();
    for (int off = 1; off < 256; off <<= 1) {
        int u = (t >= off) ? s[t - off] : 0;
        __syncthreads();
        s[t] += u;
        __syncthreads();
    }
    if (t < NBIN) binoff[t] = s[t] - v;
    if (t == 0) { binoff[NBIN] = E; rowstart[NODES] = E; }
}

// partition edges into bin-contiguous tmp; packed: src16 | dstlow8<<16
__global__ __launch_bounds__(256) void k_part(const int* __restrict__ src,
                                              const int* __restrict__ dst, int E,
                                              const int* __restrict__ offl,
                                              const int* __restrict__ binoff, int nblk,
                                              uint* __restrict__ tmp) {
    __shared__ int cur[NBIN];
    int t = threadIdx.x, blk = blockIdx.x;
    for (int i = t; i < NBIN; i += 256) cur[i] = binoff[i] + offl[i * nblk + blk];
    __syncthreads();
    int base = blk * EPB;
#pragma unroll
    for (int i = 0; i < EPB / 256; ++i) {
        int e = base + i * 256 + t;
        if (e < E) {
            int d = dst[e];
            int p = atomicAdd(&cur[d >> 8], 1);
            tmp[p] = (uint)src[e] | ((uint)(d & 0xff) << 16);
        }
    }
}

__global__ __launch_bounds__(256) void k_csr(const uint* __restrict__ tmp,
                                             const int* __restrict__ binoff,
                                             int* __restrict__ rowstart,
                                             float* __restrict__ dinv,
                                             ushort* __restrict__ esrc16) {
    __shared__ int ncnt[256], nst[256];
    int b = blockIdx.x, t = threadIdx.x;
    int e0 = binoff[b], e1 = binoff[b + 1];
    int nb0 = b << 8;
    int nn = min(256, NODES - nb0);
    ncnt[t] = 0;
    __syncthreads();
    for (int e = e0 + t; e < e1; e += 256) atomicAdd(&ncnt[(tmp[e] >> 16) & 0xff], 1);
    __syncthreads();
    int v = ncnt[t];
    nst[t] = v;
    __syncthreads();
    for (int off = 1; off < 256; off <<= 1) {
        int u = (t >= off) ? nst[t - off] : 0;
        __syncthreads();
        nst[t] += u;
        __syncthreads();
    }
    int excl = nst[t] - v;
    if (t < nn) {
        rowstart[nb0 + t] = e0 + excl;
        dinv[nb0 + t] = rsqrtf(1.0f + (float)v);
    }
    __syncthreads();
    ncnt[t] = e0 + excl;
    __syncthreads();
    for (int e = e0 + t; e < e1; e += 256) {
        uint q = tmp[e];
        int p = atomicAdd(&ncnt[(q >> 16) & 0xff], 1);
        esrc16[p] = (ushort)(q & 0xffff);
    }
}

// per-edge packed record: src16 | bf16(dinv[src])<<16 ; 4 edges/thread
__global__ void k_wfill(const ushort* __restrict__ esrc16, const float* __restrict__ dinv,
                        uint* __restrict__ epack, int E) {
    int e4 = (blockIdx.x * blockDim.x + threadIdx.x) * 4;
    if (e4 + 3 < E) {
        ushort4 s = *(const ushort4*)(esrc16 + e4);
        uint4 o;
        o.x = (uint)s.x | ((uint)f2bf(dinv[s.x]) << 16);
        o.y = (uint)s.y | ((uint)f2bf(dinv[s.y]) << 16);
        o.z = (uint)s.z | ((uint)f2bf(dinv[s.z]) << 16);
        o.w = (uint)s.w | ((uint)f2bf(dinv[s.w]) << 16);
        *(uint4*)(epack + e4) = o;
    } else {
        for (int e = e4; e < E; ++e) {
            int s = esrc16[e];
            epack[e] = (uint)s | ((uint)f2bf(dinv[s]) << 16);
        }
    }
}

// ---------------- merged weight casts ----------------
__global__ void k_cast2(const float* __restrict__ W1, ushort* __restrict__ w1t,
                        const float* __restrict__ W2, ushort* __restrict__ w2t) {
    const int N1 = 512 * 256;
    int i = blockIdx.x * blockDim.x + threadIdx.x;
    if (i < N1) {
        int r = i / 256, c = i % 256;
        w1t[(size_t)c * 512 + r] = f2bf(W1[i]);
    } else {
        int j = i - N1;
        if (j < 256 * 64) {
            int r = j / 64, c = j % 64;
            w2t[(size_t)c * 256 + r] = f2bf(W2[j]);
        }
    }
}

// ---------------- GEMM1 (single-buffer + A-reg prefetch): x @ w1t^T -> fp8 h1 ----------------
__global__ __launch_bounds__(256) void k_gemm1(const float* __restrict__ x,
                                               const ushort* __restrict__ w1t,
                                               uchar* __restrict__ h1f8, int M, int K) {
    constexpr int BM = 64, BN = 128, BK = 64;
    constexpr int NIT = 8;   // K/BK = 512/64
    __shared__ __align__(16) ushort As[BM * BK];   // 8 KB
    __shared__ __align__(16) ushort Bs[BN * BK];   // 16 KB

    int t = threadIdx.x;
    int w = t >> 6, l = t & 63;
    int wm = w & 1, wn = w >> 1;
    int bm = (blockIdx.x >> 1) * BM;
    int bn = (blockIdx.x & 1) * BN;
    int lr = l & 15, g4 = l >> 4;

    f32x4 acc[2][4] = {};

    int ar = t >> 2;
    int aq = t & 3;
    int arow_g = bm + ar;
    bool aok = arow_g < M;
    const float* ap = x + (size_t)arow_g * K + aq * 16;
    char* adst = (char*)As + ar * 128;
    int aswz = (ar & 7) << 4;

    int brow_loc = l >> 3;
    int bseg = ((l & 7) << 4) ^ (brow_loc << 4);

    float4 fa[4];
    auto loadA = [&](int k0) {
#pragma unroll
        for (int j = 0; j < 4; ++j)
            fa[j] = aok ? *(const float4*)(ap + k0 + j * 4) : make_float4(0.f, 0.f, 0.f, 0.f);
    };
    auto writeA = [&]() {
#pragma unroll
        for (int j = 0; j < 2; ++j) {
            uint p0 = cvtpk_bf16(fa[2 * j].x, fa[2 * j].y);
            uint p1 = cvtpk_bf16(fa[2 * j].z, fa[2 * j].w);
            uint p2 = cvtpk_bf16(fa[2 * j + 1].x, fa[2 * j + 1].y);
            uint p3 = cvtpk_bf16(fa[2 * j + 1].z, fa[2 * j + 1].w);
            int4 v = make_int4((int)p0, (int)p1, (int)p2, (int)p3);
            *(int4*)(adst + ((aq * 32 + j * 16) ^ aswz)) = v;
        }
    };
    auto stageB = [&](int k0) {
#pragma unroll
        for (int i = 0; i < 4; ++i) {
            int rbase = w * 32 + i * 8;
            const char* gsrc = (const char*)w1t + (size_t)(bn + rbase + brow_loc) * (K * 2) + k0 * 2 + bseg;
            __builtin_amdgcn_global_load_lds(
                (const __attribute__((address_space(1))) uint*)gsrc,
                (__attribute__((address_space(3))) uint*)((char*)Bs + rbase * 128),
                16, 0, 0);
        }
    };
    auto compute = [&]() {
#pragma unroll
        for (int ks = 0; ks < 2; ++ks) {
            short8 af[2], bfr[4];
#pragma unroll
            for (int mt = 0; mt < 2; ++mt) {
                int r = wm * 32 + mt * 16 + lr;
                af[mt] = *(const short8*)((const char*)As + r * 128 + ((ks * 64 + g4 * 16) ^ ((r & 7) << 4)));
            }
#pragma unroll
            for (int nt = 0; nt < 4; ++nt) {
                int r = wn * 64 + nt * 16 + lr;
                bfr[nt] = *(const short8*)((const char*)Bs + r * 128 + ((ks * 64 + g4 * 16) ^ ((r & 7) << 4)));
            }
#pragma unroll
            for (int mt = 0; mt < 2; ++mt)
#pragma unroll
                for (int nt = 0; nt < 4; ++nt)
                    acc[mt][nt] = __builtin_amdgcn_mfma_f32_16x16x32_bf16(af[mt], bfr[nt], acc[mt][nt], 0, 0, 0);
        }
    };

    loadA(0);
    stageB(0);
    writeA();
    __syncthreads();

    for (int it = 0; it < NIT; ++it) {
        if (it + 1 < NIT) loadA((it + 1) * BK);
        compute();
        if (it + 1 < NIT) {
            __syncthreads();
            stageB((it + 1) * BK);
            writeA();
            __syncthreads();
        }
    }

#pragma unroll
    for (int mt = 0; mt < 2; ++mt)
#pragma unroll
        for (int nt = 0; nt < 4; ++nt)
#pragma unroll
            for (int i = 0; i < 4; ++i) {
                int row = bm + wm * 32 + mt * 16 + g4 * 4 + i;
                int col = bn + wn * 64 + nt * 16 + lr;
                if (row < M) h1f8[(size_t)row * 256 + col] = f2fp8(acc[mt][nt][i]);
            }
}

// ---------------- fused agg1 + relu + GEMM2, dimension-sliced gather ----------------
// 16 nodes/block, 4 waves. Pass q (0..3) gathers only 64B slice q of each fp8 row:
// table slice = 3.2 MB < 4 MB/XCD L2 -> gathers become L2 hits. Within a wave,
// lane-group g (16 lanes) handles edge e+g's quarter; shfl_xor(16,32) folds groups.
__global__ __launch_bounds__(256) void k_agg1g2(const uchar* __restrict__ h8,
                                                const int* __restrict__ rowstart,
                                                const uint* __restrict__ ep,
                                                const float* __restrict__ dinv,
                                                const float* __restrict__ b1,
                                                const ushort* __restrict__ w2t,
                                                ushort* __restrict__ h2b) {
    __shared__ __align__(16) ushort rows[16 * 256];   // 8 KB, XOR-swizzled (r&7)<<4
    int t = threadIdx.x;
    int w = __builtin_amdgcn_readfirstlane(t >> 6);
    int lane = t & 63;
    int g = lane >> 4;        // edge group 0..3
    int d4 = lane & 15;       // dim-quad within quarter
    int nb = blockIdx.x * 16;

    // ---- phase 1: 4 dimension passes ----
    for (int q = 0; q < 4; ++q) {
        const uchar* hq = h8 + q * 64 + d4 * 4;   // per-lane slice base
        for (int i = 0; i < 4; ++i) {
            int r = w * 4 + i;
            int n = nb + r;                        // 50000 = 3125*16: always valid
            float4 acc = make_float4(0.f, 0.f, 0.f, 0.f);
            int e0 = __builtin_amdgcn_readfirstlane(rowstart[n]);
            int e1 = __builtin_amdgcn_readfirstlane(rowstart[n + 1]);
            int e = e0;
#define A1_STEP(qr, qv)                                                       \
            {                                                                 \
                float wt = __uint_as_float((qr) & 0xffff0000u);               \
                f32x2 lo = __builtin_amdgcn_cvt_pk_f32_fp8((int)(qv), false); \
                f32x2 hi = __builtin_amdgcn_cvt_pk_f32_fp8((int)(qv), true);  \
                acc.x = fmaf(wt, lo[0], acc.x);                               \
                acc.y = fmaf(wt, lo[1], acc.y);                               \
                acc.z = fmaf(wt, hi[0], acc.z);                               \
                acc.w = fmaf(wt, hi[1], acc.w);                               \
            }
            for (; e + 8 <= e1; e += 8) {
                uint qa = ep[e + g];
                uint qb = ep[e + 4 + g];
                uint va = *(const uint*)(hq + (size_t)(qa & 0xffff) * 256);
                uint vb = *(const uint*)(hq + (size_t)(qb & 0xffff) * 256);
                A1_STEP(qa, va)
                A1_STEP(qb, vb)
            }
            for (; e < e1; e += 4) {
                int ee = e + g;
                if (ee < e1) {
                    uint qr = ep[ee];
                    uint v = *(const uint*)(hq + (size_t)(qr & 0xffff) * 256);
                    A1_STEP(qr, v)
                }
            }
#undef A1_STEP
            // fold the 4 edge-groups
            acc.x += __shfl_xor(acc.x, 16); acc.y += __shfl_xor(acc.y, 16);
            acc.z += __shfl_xor(acc.z, 16); acc.w += __shfl_xor(acc.w, 16);
            acc.x += __shfl_xor(acc.x, 32); acc.y += __shfl_xor(acc.y, 32);
            acc.z += __shfl_xor(acc.z, 32); acc.w += __shfl_xor(acc.w, 32);

            if (lane < 16) {
                float dn = dinv[n];
                float s2v = dn * dn;
                uint qs = *(const uint*)(hq + (size_t)n * 256);
                f32x2 slo = __builtin_amdgcn_cvt_pk_f32_fp8((int)qs, false);
                f32x2 shi = __builtin_amdgcn_cvt_pk_f32_fp8((int)qs, true);
                const float* bq = b1 + q * 64 + d4 * 4;
                float4 bb = *(const float4*)bq;
                float rx = fmaxf(fmaf(acc.x, dn, fmaf(slo[0], s2v, bb.x)), 0.f);
                float ry = fmaxf(fmaf(acc.y, dn, fmaf(slo[1], s2v, bb.y)), 0.f);
                float rz = fmaxf(fmaf(acc.z, dn, fmaf(shi[0], s2v, bb.z)), 0.f);
                float rw = fmaxf(fmaf(acc.w, dn, fmaf(shi[1], s2v, bb.w)), 0.f);
                uint p0 = cvtpk_bf16(rx, ry);
                uint p1 = cvtpk_bf16(rz, rw);
                *(uint2*)((char*)rows + r * 512 + ((q * 128 + d4 * 8) ^ ((r & 7) << 4))) =
                    make_uint2(p0, p1);
            }
        }
    }
    __syncthreads();

    // ---- phase 2: MFMA 16 nodes x 16 cols (cols w*16..w*16+15) ----
    int lr = lane & 15, g4 = lane >> 4;
    f32x4 acc2 = {};
    const ushort* bcol = w2t + (size_t)(w * 16 + lr) * 256;
#pragma unroll
    for (int ks = 0; ks < 8; ++ks) {
        short8 af = *(const short8*)((const char*)rows + lr * 512 +
                                     ((ks * 64 + g4 * 16) ^ ((lr & 7) << 4)));
        short8 bf = *(const short8*)(bcol + ks * 32 + g4 * 8);
        acc2 = __builtin_amdgcn_mfma_f32_16x16x32_bf16(af, bf, acc2, 0, 0, 0);
    }
#pragma unroll
    for (int i = 0; i < 4; ++i) {
        int node = nb + g4 * 4 + i;
        h2b[(size_t)node * 64 + w * 16 + lr] = f2bf(acc2[i]);
    }
}

// ---------------- layer-2 aggregation + bias + log_softmax (bf16 h2) ----------------
__global__ __launch_bounds__(256) void k_agg2(const ushort* __restrict__ h,
                                              const int* __restrict__ rowstart,
                                              const uint* __restrict__ ep,
                                              const float* __restrict__ dinv,
                                              const float* __restrict__ b2,
                                              float* __restrict__ out) {
    int wave = __builtin_amdgcn_readfirstlane(threadIdx.x >> 6);
    int lane = threadIdx.x & 63;
    int n = blockIdx.x * 4 + wave;
    if (n >= NODES) return;
    const ushort* hl = h + lane;
    float acc = 0.f;
    int e0 = __builtin_amdgcn_readfirstlane(rowstart[n]);
    int e1 = __builtin_amdgcn_readfirstlane(rowstart[n + 1]);
    int e = e0;
    for (; e + 8 <= e1; e += 8) {
        uint q0 = ep[e],     q1 = ep[e + 1], q2 = ep[e + 2], q3 = ep[e + 3];
        uint q4 = ep[e + 4], q5 = ep[e + 5], q6 = ep[e + 6], q7 = ep[e + 7];
        float v0 = bf2f(hl[(size_t)(q0 & 0xffff) * 64]);
        float v1 = bf2f(hl[(size_t)(q1 & 0xffff) * 64]);
        float v2 = bf2f(hl[(size_t)(q2 & 0xffff) * 64]);
        float v3 = bf2f(hl[(size_t)(q3 & 0xffff) * 64]);
        float v4 = bf2f(hl[(size_t)(q4 & 0xffff) * 64]);
        float v5 = bf2f(hl[(size_t)(q5 & 0xffff) * 64]);
        float v6 = bf2f(hl[(size_t)(q6 & 0xffff) * 64]);
        float v7 = bf2f(hl[(size_t)(q7 & 0xffff) * 64]);
        acc = fmaf(__uint_as_float(q0 & 0xffff0000u), v0, acc);
        acc = fmaf(__uint_as_float(q1 & 0xffff0000u), v1, acc);
        acc = fmaf(__uint_as_float(q2 & 0xffff0000u), v2, acc);
        acc = fmaf(__uint_as_float(q3 & 0xffff0000u), v3, acc);
        acc = fmaf(__uint_as_float(q4 & 0xffff0000u), v4, acc);
        acc = fmaf(__uint_as_float(q5 & 0xffff0000u), v5, acc);
        acc = fmaf(__uint_as_float(q6 & 0xffff0000u), v6, acc);
        acc = fmaf(__uint_as_float(q7 & 0xffff0000u), v7, acc);
    }
    for (; e < e1; ++e) {
        uint q = ep[e];
        acc = fmaf(__uint_as_float(q & 0xffff0000u), bf2f(hl[(size_t)(q & 0xffff) * 64]), acc);
    }
    float dn = dinv[n];
    float r = fmaf(acc, dn, fmaf(bf2f(hl[(size_t)n * 64]), dn * dn, b2[lane]));
    float m = r;
#pragma unroll
    for (int off = 32; off; off >>= 1) m = fmaxf(m, __shfl_xor(m, off));
    float ex = __expf(r - m);
    float ssum = ex;
#pragma unroll
    for (int off = 32; off; off >>= 1) ssum += __shfl_xor(ssum, off);
    out[(size_t)n * 64 + lane] = r - m - __logf(ssum);
}

// ---------------- launch ----------------

extern "C" void kernel_launch(void* const* d_in, const int* in_sizes, int n_in,
                              void* d_out, int out_size, void* d_ws, size_t ws_size,
                              hipStream_t stream) {
    const float* x  = (const float*)d_in[0];
    const float* W1 = (const float*)d_in[1];
    const float* b1 = (const float*)d_in[2];
    const float* W2 = (const float*)d_in[3];
    const float* b2 = (const float*)d_in[4];
    const int*   ei = (const int*)d_in[5];
    int E = in_sizes[5] / 2;
    const int* src = ei;
    const int* dst = ei + E;
    float* out = (float*)d_out;

    int nblk = (E + EPB - 1) / EPB;   // 391

    char* wsp = (char*)d_ws;
    auto alloc = [&](size_t bytes) {
        char* p = wsp;
        wsp += (bytes + 255) & ~(size_t)255;
        return p;
    };
    int*    hist     = (int*)alloc((size_t)NBIN * nblk * 4);
    int*    offl     = (int*)alloc((size_t)NBIN * nblk * 4);
    int*    btot     = (int*)alloc((size_t)NBIN * 4);
    int*    binoff   = (int*)alloc((size_t)(NBIN + 1) * 4);
    int*    rowstart = (int*)alloc((size_t)(NODES + 1) * 4);
    float*  dinv     = (float*)alloc((size_t)NODES * 4);
    uint*   tmp      = (uint*)alloc((size_t)E * 4);
    ushort* esrc16   = (ushort*)alloc((size_t)E * 2);
    uint*   epack    = (uint*)alloc((size_t)E * 4);
    ushort* w1t      = (ushort*)alloc((size_t)256 * 512 * 2);
    ushort* w2t      = (ushort*)alloc((size_t)64 * 256 * 2);
    uchar*  h1f8     = (uchar*)alloc((size_t)NODES * 256);
    ushort* h2b      = (ushort*)alloc((size_t)NODES * 64 * 2);

    // ---- CSR build ----
    k_hist<<<nblk, 256, 0, stream>>>(dst, E, hist, nblk);
    k_scanbin<<<NBIN, 1024, 0, stream>>>(hist, offl, btot, nblk);
    k_scanoff<<<1, 256, 0, stream>>>(btot, binoff, rowstart, E);
    k_part<<<nblk, 256, 0, stream>>>(src, dst, E, offl, binoff, nblk, tmp);
    k_csr<<<NBIN, 256, 0, stream>>>(tmp, binoff, rowstart, dinv, esrc16);
    k_wfill<<<(E / 4 + 255) / 256, 256, 0, stream>>>(esrc16, dinv, epack, E);

    // ---- weight casts (merged) ----
    k_cast2<<<(512 * 256 + 256 * 64 + 255) / 256, 256, 0, stream>>>(W1, w1t, W2, w2t);

    // ---- layer 1 GEMM ----
    k_gemm1<<<((NODES + 63) / 64) * 2, 256, 0, stream>>>(x, w1t, h1f8, NODES, 512);

    // ---- fused agg1 + relu + GEMM2 -> h2 (dimension-sliced gather) ----
    k_agg1g2<<<NODES / 16, 256, 0, stream>>>(h1f8, rowstart, epack, dinv, b1, w2t, h2b);

    // ---- layer 2 agg + log_softmax ----
    k_agg2<<<(NODES + 3) / 4, 256, 0, stream>>>(h2b, rowstart, epack, dinv, b2, out);
}

// Round 21
// 196.381 us; speedup vs baseline: 1.4157x; 1.4157x over previous
//
#include <hip/hip_runtime.h>

#define NODES 50000
#define NBIN 196          // ceil(50000/256) dst-bins of 256 nodes
#define EPB 4096          // edges per partition block

typedef __attribute__((ext_vector_type(8))) short short8;
typedef __attribute__((ext_vector_type(4))) float f32x4;
typedef __attribute__((ext_vector_type(2))) float f32x2;

__device__ __forceinline__ ushort f2bf(float f) {
    uint u = __float_as_uint(f);
    uint r = (u + 0x7fffu + ((u >> 16) & 1u)) >> 16;
    return (ushort)r;
}
__device__ __forceinline__ float bf2f(ushort u) {
    return __uint_as_float(((uint)u) << 16);
}
__device__ __forceinline__ uchar f2fp8(float f) {
    return (uchar)(__builtin_amdgcn_cvt_pk_fp8_f32(f, f, 0, false) & 0xff);
}
// HW packed f32x2 -> bf16x2 (RNE), one VALU op
__device__ __forceinline__ uint cvtpk_bf16(float lo, float hi) {
    uint r;
    asm("v_cvt_pk_bf16_f32 %0, %1, %2" : "=v"(r) : "v"(lo), "v"(hi));
    return r;
}

// ---------------- atomic-free two-level CSR build ----------------

__global__ __launch_bounds__(256) void k_hist(const int* __restrict__ dst, int E,
                                              int* __restrict__ hist, int nblk) {
    __shared__ int h[NBIN];
    int t = threadIdx.x;
    for (int i = t; i < NBIN; i += 256) h[i] = 0;
    __syncthreads();
    int base = blockIdx.x * EPB;
#pragma unroll
    for (int i = 0; i < EPB / 256; ++i) {
        int e = base + i * 256 + t;
        if (e < E) atomicAdd(&h[dst[e] >> 8], 1);
    }
    __syncthreads();
    for (int i = t; i < NBIN; i += 256) hist[i * nblk + blockIdx.x] = h[i];
}

__global__ __launch_bounds__(1024) void k_scanbin(const int* __restrict__ hist,
                                                  int* __restrict__ offl,
                                                  int* __restrict__ btot, int nblk) {
    __shared__ int s[1024];
    int b = blockIdx.x, t = threadIdx.x;
    int v = (t < nblk) ? hist[b * nblk + t] : 0;
    s[t] = v;
    __syncthreads();
    for (int off = 1; off < 1024; off <<= 1) {
        int u = (t >= off) ? s[t - off] : 0;
        __syncthreads();
        s[t] += u;
        __syncthreads();
    }
    if (t < nblk) offl[b * nblk + t] = s[t] - v;
    if (t == 1023) btot[b] = s[1023];
}

__global__ __launch_bounds__(256) void k_scanoff(const int* __restrict__ btot,
                                                 int* __restrict__ binoff,
                                                 int* __restrict__ rowstart, int E) {
    __shared__ int s[256];
    int t = threadIdx.x;
    int v = (t < NBIN) ? btot[t] : 0;
    s[t] = v;
    __syncthreads();
    for (int off = 1; off < 256; off <<= 1) {
        int u = (t >= off) ? s[t - off] : 0;
        __syncthreads();
        s[t] += u;
        __syncthreads();
    }
    if (t < NBIN) binoff[t] = s[t] - v;
    if (t == 0) { binoff[NBIN] = E; rowstart[NODES] = E; }
}

// partition edges into bin-contiguous tmp; packed: src16 | dstlow8<<16
__global__ __launch_bounds__(256) void k_part(const int* __restrict__ src,
                                              const int* __restrict__ dst, int E,
                                              const int* __restrict__ offl,
                                              const int* __restrict__ binoff, int nblk,
                                              uint* __restrict__ tmp) {
    __shared__ int cur[NBIN];
    int t = threadIdx.x, blk = blockIdx.x;
    for (int i = t; i < NBIN; i += 256) cur[i] = binoff[i] + offl[i * nblk + blk];
    __syncthreads();
    int base = blk * EPB;
#pragma unroll
    for (int i = 0; i < EPB / 256; ++i) {
        int e = base + i * 256 + t;
        if (e < E) {
            int d = dst[e];
            int p = atomicAdd(&cur[d >> 8], 1);
            tmp[p] = (uint)src[e] | ((uint)(d & 0xff) << 16);
        }
    }
}

__global__ __launch_bounds__(256) void k_csr(const uint* __restrict__ tmp,
                                             const int* __restrict__ binoff,
                                             int* __restrict__ rowstart,
                                             float* __restrict__ dinv,
                                             ushort* __restrict__ esrc16) {
    __shared__ int ncnt[256], nst[256];
    int b = blockIdx.x, t = threadIdx.x;
    int e0 = binoff[b], e1 = binoff[b + 1];
    int nb0 = b << 8;
    int nn = min(256, NODES - nb0);
    ncnt[t] = 0;
    __syncthreads();
    for (int e = e0 + t; e < e1; e += 256) atomicAdd(&ncnt[(tmp[e] >> 16) & 0xff], 1);
    __syncthreads();
    int v = ncnt[t];
    nst[t] = v;
    __syncthreads();
    for (int off = 1; off < 256; off <<= 1) {
        int u = (t >= off) ? nst[t - off] : 0;
        __syncthreads();
        nst[t] += u;
        __syncthreads();
    }
    int excl = nst[t] - v;
    if (t < nn) {
        rowstart[nb0 + t] = e0 + excl;
        dinv[nb0 + t] = rsqrtf(1.0f + (float)v);
    }
    __syncthreads();
    ncnt[t] = e0 + excl;
    __syncthreads();
    for (int e = e0 + t; e < e1; e += 256) {
        uint q = tmp[e];
        int p = atomicAdd(&ncnt[(q >> 16) & 0xff], 1);
        esrc16[p] = (ushort)(q & 0xffff);
    }
}

// per-edge packed record: src16 | bf16(dinv[src])<<16 ; 4 edges/thread
__global__ void k_wfill(const ushort* __restrict__ esrc16, const float* __restrict__ dinv,
                        uint* __restrict__ epack, int E) {
    int e4 = (blockIdx.x * blockDim.x + threadIdx.x) * 4;
    if (e4 + 3 < E) {
        ushort4 s = *(const ushort4*)(esrc16 + e4);
        uint4 o;
        o.x = (uint)s.x | ((uint)f2bf(dinv[s.x]) << 16);
        o.y = (uint)s.y | ((uint)f2bf(dinv[s.y]) << 16);
        o.z = (uint)s.z | ((uint)f2bf(dinv[s.z]) << 16);
        o.w = (uint)s.w | ((uint)f2bf(dinv[s.w]) << 16);
        *(uint4*)(epack + e4) = o;
    } else {
        for (int e = e4; e < E; ++e) {
            int s = esrc16[e];
            epack[e] = (uint)s | ((uint)f2bf(dinv[s]) << 16);
        }
    }
}

// ---------------- merged weight casts ----------------
__global__ void k_cast2(const float* __restrict__ W1, ushort* __restrict__ w1t,
                        const float* __restrict__ W2, ushort* __restrict__ w2t) {
    const int N1 = 512 * 256;
    int i = blockIdx.x * blockDim.x + threadIdx.x;
    if (i < N1) {
        int r = i / 256, c = i % 256;
        w1t[(size_t)c * 512 + r] = f2bf(W1[i]);
    } else {
        int j = i - N1;
        if (j < 256 * 64) {
            int r = j / 64, c = j % 64;
            w2t[(size_t)c * 256 + r] = f2bf(W2[j]);
        }
    }
}

// ---------------- GEMM1 (single-buffer + A-reg prefetch): x @ w1t^T -> fp8 h1 ----------------
__global__ __launch_bounds__(256) void k_gemm1(const float* __restrict__ x,
                                               const ushort* __restrict__ w1t,
                                               uchar* __restrict__ h1f8, int M, int K) {
    constexpr int BM = 64, BN = 128, BK = 64;
    constexpr int NIT = 8;   // K/BK = 512/64
    __shared__ __align__(16) ushort As[BM * BK];   // 8 KB
    __shared__ __align__(16) ushort Bs[BN * BK];   // 16 KB

    int t = threadIdx.x;
    int w = t >> 6, l = t & 63;
    int wm = w & 1, wn = w >> 1;
    int bm = (blockIdx.x >> 1) * BM;
    int bn = (blockIdx.x & 1) * BN;
    int lr = l & 15, g4 = l >> 4;

    f32x4 acc[2][4] = {};

    int ar = t >> 2;
    int aq = t & 3;
    int arow_g = bm + ar;
    bool aok = arow_g < M;
    const float* ap = x + (size_t)arow_g * K + aq * 16;
    char* adst = (char*)As + ar * 128;
    int aswz = (ar & 7) << 4;

    int brow_loc = l >> 3;
    int bseg = ((l & 7) << 4) ^ (brow_loc << 4);

    float4 fa[4];
    auto loadA = [&](int k0) {
#pragma unroll
        for (int j = 0; j < 4; ++j)
            fa[j] = aok ? *(const float4*)(ap + k0 + j * 4) : make_float4(0.f, 0.f, 0.f, 0.f);
    };
    auto writeA = [&]() {
#pragma unroll
        for (int j = 0; j < 2; ++j) {
            uint p0 = cvtpk_bf16(fa[2 * j].x, fa[2 * j].y);
            uint p1 = cvtpk_bf16(fa[2 * j].z, fa[2 * j].w);
            uint p2 = cvtpk_bf16(fa[2 * j + 1].x, fa[2 * j + 1].y);
            uint p3 = cvtpk_bf16(fa[2 * j + 1].z, fa[2 * j + 1].w);
            int4 v = make_int4((int)p0, (int)p1, (int)p2, (int)p3);
            *(int4*)(adst + ((aq * 32 + j * 16) ^ aswz)) = v;
        }
    };
    auto stageB = [&](int k0) {
#pragma unroll
        for (int i = 0; i < 4; ++i) {
            int rbase = w * 32 + i * 8;
            const char* gsrc = (const char*)w1t + (size_t)(bn + rbase + brow_loc) * (K * 2) + k0 * 2 + bseg;
            __builtin_amdgcn_global_load_lds(
                (const __attribute__((address_space(1))) uint*)gsrc,
                (__attribute__((address_space(3))) uint*)((char*)Bs + rbase * 128),
                16, 0, 0);
        }
    };
    auto compute = [&]() {
#pragma unroll
        for (int ks = 0; ks < 2; ++ks) {
            short8 af[2], bfr[4];
#pragma unroll
            for (int mt = 0; mt < 2; ++mt) {
                int r = wm * 32 + mt * 16 + lr;
                af[mt] = *(const short8*)((const char*)As + r * 128 + ((ks * 64 + g4 * 16) ^ ((r & 7) << 4)));
            }
#pragma unroll
            for (int nt = 0; nt < 4; ++nt) {
                int r = wn * 64 + nt * 16 + lr;
                bfr[nt] = *(const short8*)((const char*)Bs + r * 128 + ((ks * 64 + g4 * 16) ^ ((r & 7) << 4)));
            }
#pragma unroll
            for (int mt = 0; mt < 2; ++mt)
#pragma unroll
                for (int nt = 0; nt < 4; ++nt)
                    acc[mt][nt] = __builtin_amdgcn_mfma_f32_16x16x32_bf16(af[mt], bfr[nt], acc[mt][nt], 0, 0, 0);
        }
    };

    loadA(0);
    stageB(0);
    writeA();
    __syncthreads();

    for (int it = 0; it < NIT; ++it) {
        if (it + 1 < NIT) loadA((it + 1) * BK);
        compute();
        if (it + 1 < NIT) {
            __syncthreads();
            stageB((it + 1) * BK);
            writeA();
            __syncthreads();
        }
    }

#pragma unroll
    for (int mt = 0; mt < 2; ++mt)
#pragma unroll
        for (int nt = 0; nt < 4; ++nt)
#pragma unroll
            for (int i = 0; i < 4; ++i) {
                int row = bm + wm * 32 + mt * 16 + g4 * 4 + i;
                int col = bn + wn * 64 + nt * 16 + lr;
                if (row < M) h1f8[(size_t)row * 256 + col] = f2fp8(acc[mt][nt][i]);
            }
}

// ---------------- fused layer-1 agg + relu + GEMM2: h2 = relu(agg1) @ W2t^T ----------------
// 16 nodes per block (4 waves x 4 nodes sequential). Rows parked in swizzled LDS;
// each wave then computes its 16 output cols via 8x mfma_16x16x32 (B = w2t, L2-hot).
__global__ __launch_bounds__(256) void k_agg1g2(const uchar* __restrict__ h8,
                                                const int* __restrict__ rowstart,
                                                const uint* __restrict__ ep,
                                                const float* __restrict__ dinv,
                                                const float* __restrict__ b1,
                                                const ushort* __restrict__ w2t,
                                                ushort* __restrict__ h2b) {
    __shared__ __align__(16) ushort rows[16 * 256];   // 8 KB, XOR-swizzled (r&7)<<4
    int t = threadIdx.x;
    int w = __builtin_amdgcn_readfirstlane(t >> 6);
    int lane = t & 63;
    int nb = blockIdx.x * 16;
    const uchar* hl = h8 + lane * 4;

    // ---- phase 1: aggregate 4 nodes per wave, rows -> LDS ----
    for (int i = 0; i < 4; ++i) {
        int r = w * 4 + i;          // tile row
        int n = nb + r;             // global node (50000 = 3125*16, always valid)
        float4 acc = make_float4(0.f, 0.f, 0.f, 0.f);
        int e0 = __builtin_amdgcn_readfirstlane(rowstart[n]);
        int e1 = __builtin_amdgcn_readfirstlane(rowstart[n + 1]);
        int e = e0;
#define A1_STEP(q, qv)                                                        \
        {                                                                     \
            float wt = __uint_as_float((q) & 0xffff0000u);                    \
            f32x2 lo = __builtin_amdgcn_cvt_pk_f32_fp8((int)(qv), false);     \
            f32x2 hi = __builtin_amdgcn_cvt_pk_f32_fp8((int)(qv), true);      \
            acc.x = fmaf(wt, lo[0], acc.x);                                   \
            acc.y = fmaf(wt, lo[1], acc.y);                                   \
            acc.z = fmaf(wt, hi[0], acc.z);                                   \
            acc.w = fmaf(wt, hi[1], acc.w);                                   \
        }
        for (; e + 8 <= e1; e += 8) {
            uint q0 = ep[e],     q1 = ep[e + 1], q2 = ep[e + 2], q3 = ep[e + 3];
            uint q4 = ep[e + 4], q5 = ep[e + 5], q6 = ep[e + 6], q7 = ep[e + 7];
            uint v0 = *(const uint*)(hl + (size_t)(q0 & 0xffff) * 256);
            uint v1 = *(const uint*)(hl + (size_t)(q1 & 0xffff) * 256);
            uint v2 = *(const uint*)(hl + (size_t)(q2 & 0xffff) * 256);
            uint v3 = *(const uint*)(hl + (size_t)(q3 & 0xffff) * 256);
            uint v4 = *(const uint*)(hl + (size_t)(q4 & 0xffff) * 256);
            uint v5 = *(const uint*)(hl + (size_t)(q5 & 0xffff) * 256);
            uint v6 = *(const uint*)(hl + (size_t)(q6 & 0xffff) * 256);
            uint v7 = *(const uint*)(hl + (size_t)(q7 & 0xffff) * 256);
            A1_STEP(q0, v0) A1_STEP(q1, v1) A1_STEP(q2, v2) A1_STEP(q3, v3)
            A1_STEP(q4, v4) A1_STEP(q5, v5) A1_STEP(q6, v6) A1_STEP(q7, v7)
        }
        for (; e < e1; ++e) {
            uint q = ep[e];
            uint v = *(const uint*)(hl + (size_t)(q & 0xffff) * 256);
            A1_STEP(q, v)
        }
#undef A1_STEP
        float dn = dinv[n];
        float s2v = dn * dn;
        uint qs = *(const uint*)(hl + (size_t)n * 256);
        f32x2 slo = __builtin_amdgcn_cvt_pk_f32_fp8((int)qs, false);
        f32x2 shi = __builtin_amdgcn_cvt_pk_f32_fp8((int)qs, true);
        float4 bb = *(const float4*)(b1 + lane * 4);
        float rx = fmaxf(fmaf(acc.x, dn, fmaf(slo[0], s2v, bb.x)), 0.f);
        float ry = fmaxf(fmaf(acc.y, dn, fmaf(slo[1], s2v, bb.y)), 0.f);
        float rz = fmaxf(fmaf(acc.z, dn, fmaf(shi[0], s2v, bb.z)), 0.f);
        float rw = fmaxf(fmaf(acc.w, dn, fmaf(shi[1], s2v, bb.w)), 0.f);
        uint p0 = cvtpk_bf16(rx, ry);
        uint p1 = cvtpk_bf16(rz, rw);
        *(uint2*)((char*)rows + r * 512 + ((lane * 8) ^ ((r & 7) << 4))) =
            make_uint2(p0, p1);
    }
    __syncthreads();

    // ---- phase 2: MFMA 16 nodes x 16 cols (cols w*16..w*16+15) ----
    int lr = lane & 15, g4 = lane >> 4;
    f32x4 acc2 = {};
    const ushort* bcol = w2t + (size_t)(w * 16 + lr) * 256;
#pragma unroll
    for (int ks = 0; ks < 8; ++ks) {
        short8 af = *(const short8*)((const char*)rows + lr * 512 +
                                     ((ks * 64 + g4 * 16) ^ ((lr & 7) << 4)));
        short8 bf = *(const short8*)(bcol + ks * 32 + g4 * 8);
        acc2 = __builtin_amdgcn_mfma_f32_16x16x32_bf16(af, bf, acc2, 0, 0, 0);
    }
#pragma unroll
    for (int i = 0; i < 4; ++i) {
        int node = nb + g4 * 4 + i;
        h2b[(size_t)node * 64 + w * 16 + lr] = f2bf(acc2[i]);
    }
}

// ---------------- layer-2 aggregation + bias + log_softmax (bf16 h2) ----------------
__global__ __launch_bounds__(256) void k_agg2(const ushort* __restrict__ h,
                                              const int* __restrict__ rowstart,
                                              const uint* __restrict__ ep,
                                              const float* __restrict__ dinv,
                                              const float* __restrict__ b2,
                                              float* __restrict__ out) {
    int wave = __builtin_amdgcn_readfirstlane(threadIdx.x >> 6);
    int lane = threadIdx.x & 63;
    int n = blockIdx.x * 4 + wave;
    if (n >= NODES) return;
    const ushort* hl = h + lane;
    float acc = 0.f;
    int e0 = __builtin_amdgcn_readfirstlane(rowstart[n]);
    int e1 = __builtin_amdgcn_readfirstlane(rowstart[n + 1]);
    int e = e0;
    for (; e + 8 <= e1; e += 8) {
        uint q0 = ep[e],     q1 = ep[e + 1], q2 = ep[e + 2], q3 = ep[e + 3];
        uint q4 = ep[e + 4], q5 = ep[e + 5], q6 = ep[e + 6], q7 = ep[e + 7];
        float v0 = bf2f(hl[(size_t)(q0 & 0xffff) * 64]);
        float v1 = bf2f(hl[(size_t)(q1 & 0xffff) * 64]);
        float v2 = bf2f(hl[(size_t)(q2 & 0xffff) * 64]);
        float v3 = bf2f(hl[(size_t)(q3 & 0xffff) * 64]);
        float v4 = bf2f(hl[(size_t)(q4 & 0xffff) * 64]);
        float v5 = bf2f(hl[(size_t)(q5 & 0xffff) * 64]);
        float v6 = bf2f(hl[(size_t)(q6 & 0xffff) * 64]);
        float v7 = bf2f(hl[(size_t)(q7 & 0xffff) * 64]);
        acc = fmaf(__uint_as_float(q0 & 0xffff0000u), v0, acc);
        acc = fmaf(__uint_as_float(q1 & 0xffff0000u), v1, acc);
        acc = fmaf(__uint_as_float(q2 & 0xffff0000u), v2, acc);
        acc = fmaf(__uint_as_float(q3 & 0xffff0000u), v3, acc);
        acc = fmaf(__uint_as_float(q4 & 0xffff0000u), v4, acc);
        acc = fmaf(__uint_as_float(q5 & 0xffff0000u), v5, acc);
        acc = fmaf(__uint_as_float(q6 & 0xffff0000u), v6, acc);
        acc = fmaf(__uint_as_float(q7 & 0xffff0000u), v7, acc);
    }
    for (; e < e1; ++e) {
        uint q = ep[e];
        acc = fmaf(__uint_as_float(q & 0xffff0000u), bf2f(hl[(size_t)(q & 0xffff) * 64]), acc);
    }
    float dn = dinv[n];
    float r = fmaf(acc, dn, fmaf(bf2f(hl[(size_t)n * 64]), dn * dn, b2[lane]));
    float m = r;
#pragma unroll
    for (int off = 32; off; off >>= 1) m = fmaxf(m, __shfl_xor(m, off));
    float ex = __expf(r - m);
    float ssum = ex;
#pragma unroll
    for (int off = 32; off; off >>= 1) ssum += __shfl_xor(ssum, off);
    out[(size_t)n * 64 + lane] = r - m - __logf(ssum);
}

// ---------------- launch ----------------

extern "C" void kernel_launch(void* const* d_in, const int* in_sizes, int n_in,
                              void* d_out, int out_size, void* d_ws, size_t ws_size,
                              hipStream_t stream) {
    const float* x  = (const float*)d_in[0];
    const float* W1 = (const float*)d_in[1];
    const float* b1 = (const float*)d_in[2];
    const float* W2 = (const float*)d_in[3];
    const float* b2 = (const float*)d_in[4];
    const int*   ei = (const int*)d_in[5];
    int E = in_sizes[5] / 2;
    const int* src = ei;
    const int* dst = ei + E;
    float* out = (float*)d_out;

    int nblk = (E + EPB - 1) / EPB;   // 391

    char* wsp = (char*)d_ws;
    auto alloc = [&](size_t bytes) {
        char* p = wsp;
        wsp += (bytes + 255) & ~(size_t)255;
        return p;
    };
    int*    hist     = (int*)alloc((size_t)NBIN * nblk * 4);
    int*    offl     = (int*)alloc((size_t)NBIN * nblk * 4);
    int*    btot     = (int*)alloc((size_t)NBIN * 4);
    int*    binoff   = (int*)alloc((size_t)(NBIN + 1) * 4);
    int*    rowstart = (int*)alloc((size_t)(NODES + 1) * 4);
    float*  dinv     = (float*)alloc((size_t)NODES * 4);
    uint*   tmp      = (uint*)alloc((size_t)E * 4);
    ushort* esrc16   = (ushort*)alloc((size_t)E * 2);
    uint*   epack    = (uint*)alloc((size_t)E * 4);
    ushort* w1t      = (ushort*)alloc((size_t)256 * 512 * 2);
    ushort* w2t      = (ushort*)alloc((size_t)64 * 256 * 2);
    uchar*  h1f8     = (uchar*)alloc((size_t)NODES * 256);
    ushort* h2b      = (ushort*)alloc((size_t)NODES * 64 * 2);

    // ---- CSR build ----
    k_hist<<<nblk, 256, 0, stream>>>(dst, E, hist, nblk);
    k_scanbin<<<NBIN, 1024, 0, stream>>>(hist, offl, btot, nblk);
    k_scanoff<<<1, 256, 0, stream>>>(btot, binoff, rowstart, E);
    k_part<<<nblk, 256, 0, stream>>>(src, dst, E, offl, binoff, nblk, tmp);
    k_csr<<<NBIN, 256, 0, stream>>>(tmp, binoff, rowstart, dinv, esrc16);
    k_wfill<<<(E / 4 + 255) / 256, 256, 0, stream>>>(esrc16, dinv, epack, E);

    // ---- weight casts (merged) ----
    k_cast2<<<(512 * 256 + 256 * 64 + 255) / 256, 256, 0, stream>>>(W1, w1t, W2, w2t);

    // ---- layer 1 GEMM ----
    k_gemm1<<<((NODES + 63) / 64) * 2, 256, 0, stream>>>(x, w1t, h1f8, NODES, 512);

    // ---- fused agg1 + relu + GEMM2 -> h2 ----
    k_agg1g2<<<NODES / 16, 256, 0, stream>>>(h1f8, rowstart, epack, dinv, b1, w2t, h2b);

    // ---- layer 2 agg + log_softmax ----
    k_agg2<<<(NODES + 3) / 4, 256, 0, stream>>>(h2b, rowstart, epack, dinv, b2, out);
}